// Round 3
// baseline (1722.465 us; speedup 1.0000x reference)
//
#include <hip/hip_runtime.h>
#include <hip/hip_bf16.h>
#include <stdint.h>

// Problem constants
#define B_   2
#define T_   2048
#define D_   1024
#define H_   16
#define F_   4096
#define V_   32000
#define HD_  64
#define BT_  (B_ * T_)   // 4096

typedef __attribute__((ext_vector_type(8))) short short8;
typedef __attribute__((ext_vector_type(4))) float f32x4;

#define MFMA16(a, b, c) __builtin_amdgcn_mfma_f32_16x16x32_bf16((a), (b), (c), 0, 0, 0)

// float -> bf16 bits, round-to-nearest-even
__device__ __forceinline__ unsigned short f2bf(float f) {
    unsigned int u = __builtin_bit_cast(unsigned int, f);
    u = (u + 0x7fffu + ((u >> 16) & 1u)) >> 16;
    return (unsigned short)u;
}

typedef __attribute__((address_space(1))) void* as1_void;
typedef __attribute__((address_space(3))) void* as3_void;

// async global->LDS, 16B per lane; LDS dest = wave-uniform base + lane*16
__device__ __forceinline__ void gl_lds16(const void* g, void* l) {
    __builtin_amdgcn_global_load_lds((as1_void)(uintptr_t)g, (as3_void)l, 16, 0, 0);
}

// XCD-aware swizzle of a linear workgroup id (requires nwg % 8 == 0)
__device__ __forceinline__ int xcd_swz(int wg, int nwg) {
    return (wg & 7) * (nwg >> 3) + (wg >> 3);
}

// ---------------------------------------------------------------------------
// Weight transpose + f32->bf16:  W[K,N] f32  ->  Wt[N,K] bf16
// ---------------------------------------------------------------------------
__device__ __forceinline__ void transpose_tile(
    const float* __restrict__ W, unsigned short* __restrict__ Wt,
    int K, int N, int bx, int by, int tid)
{
    __shared__ float tile[64][65];
    const int n0 = bx * 64, k0 = by * 64;
    const int tx = tid & 63, ty = tid >> 6;
#pragma unroll
    for (int i = 0; i < 64; i += 4)
        tile[ty + i][tx] = W[(size_t)(k0 + ty + i) * N + n0 + tx];
    __syncthreads();
#pragma unroll
    for (int i = 0; i < 64; i += 4) {
        const int n = ty + i;
        Wt[(size_t)(n0 + n) * K + k0 + tx] = f2bf(tile[tx][n]);
    }
}

__global__ __launch_bounds__(256) void k_transpose_cvt(
    const float* __restrict__ W, unsigned short* __restrict__ Wt, int K, int N)
{
    transpose_tile(W, Wt, K, N, blockIdx.x, blockIdx.y, threadIdx.x);
}

struct TP4 { const float* src[4]; unsigned short* dst[4]; };

__global__ __launch_bounds__(256) void k_transpose_cvt4(TP4 a, int K, int N)
{
    transpose_tile(a.src[blockIdx.z], a.dst[blockIdx.z], K, N,
                   blockIdx.x, blockIdx.y, threadIdx.x);
}

// ---------------------------------------------------------------------------
// Embedding + sinusoidal positional encoding -> bf16 h[BT, D]
// ---------------------------------------------------------------------------
__global__ __launch_bounds__(256) void k_embed(
    const int* __restrict__ x, const float* __restrict__ emb,
    unsigned short* __restrict__ h)
{
    const int m = blockIdx.x;            // 0..BT-1
    const int t = m & (T_ - 1);
    const int tok = x[m];
    const float* e = emb + (size_t)tok * D_;
    unsigned short* hr = h + (size_t)m * D_;
    const float c0 = -9.210340371976184f / 1024.0f;   // -ln(10000)/D
    const int d = threadIdx.x * 4;                    // 256*4 = 1024 = D
    const float4 ev = *(const float4*)(e + d);
    const float dv0 = __expf((float)d * c0);
    const float dv1 = __expf((float)(d + 2) * c0);
    const float a0 = (float)t * dv0, a1 = (float)t * dv1;
    ushort4 ov;
    ov.x = f2bf(ev.x + sinf(a0));
    ov.y = f2bf(ev.y + cosf(a0));
    ov.z = f2bf(ev.z + sinf(a1));
    ov.w = f2bf(ev.w + cosf(a1));
    *(ushort4*)(hr + d) = ov;
}

// ---------------------------------------------------------------------------
// GEMM: C[M,N] = A[M,K](bf16) @ Bt[N,K](bf16)^T + bias.
// m97 structure: 128x128 tile, 4 waves (64x64 each), BK=32, global_load_lds.
// ---------------------------------------------------------------------------
#define MODE_F32        0
#define MODE_RELU_BF16  1
#define MODE_LOGITS     2   // f32 + fused per-wave softmax partials (pm/pl)

template <int MODE>
__global__ __launch_bounds__(256, 2) void k_gemm(
    const unsigned short* __restrict__ A,   // [M,K]
    const unsigned short* __restrict__ Bt,  // [N,K]
    const float* __restrict__ bias,         // [N]
    void* __restrict__ Cout,
    int M, int N, int K,
    float* __restrict__ pm, float* __restrict__ pl)
{
    __shared__ unsigned short As[128 * 32];
    __shared__ unsigned short Bs[128 * 32];
    const int tid = threadIdx.x;
    const int lane = tid & 63;
    const int w = tid >> 6;
    const int wr = w >> 1, wc = w & 1;

    const int gx = gridDim.x;
    const int swz = xcd_swz(blockIdx.y * gx + blockIdx.x, gx * gridDim.y);
    const int m0 = (swz / gx) * 128, n0 = (swz % gx) * 128;

    f32x4 acc[4][4];
#pragma unroll
    for (int i = 0; i < 4; i++)
#pragma unroll
        for (int j = 0; j < 4; j++)
            acc[i][j] = (f32x4){0.f, 0.f, 0.f, 0.f};

    // staging: 8 chunks of 16 rows x 32 cols; wave w owns chunks w and w+4
    const int crow = lane >> 2;            // row within chunk
    const int ccol = (lane & 3) * 8;       // k element offset
    const unsigned short* gA0 = A  + (size_t)(m0 + w * 16 + crow) * K + ccol;
    const unsigned short* gA1 = A  + (size_t)(m0 + (w + 4) * 16 + crow) * K + ccol;
    const unsigned short* gB0 = Bt + (size_t)(n0 + w * 16 + crow) * K + ccol;
    const unsigned short* gB1 = Bt + (size_t)(n0 + (w + 4) * 16 + crow) * K + ccol;
    unsigned short* lA0 = As + w * 512;
    unsigned short* lA1 = As + (w + 4) * 512;
    unsigned short* lB0 = Bs + w * 512;
    unsigned short* lB1 = Bs + (w + 4) * 512;

    const int fr = lane & 15;              // fragment row/col
    const int kb = (lane >> 4) * 8;        // fragment k offset

    for (int k0 = 0; k0 < K; k0 += 32) {
        gl_lds16(gA0 + k0, lA0);
        gl_lds16(gA1 + k0, lA1);
        gl_lds16(gB0 + k0, lB0);
        gl_lds16(gB1 + k0, lB1);
        __syncthreads();
        short8 af[4], bfv[4];
#pragma unroll
        for (int m = 0; m < 4; m++)
            af[m] = *(const short8*)(As + (size_t)(wr * 64 + m * 16 + fr) * 32 + kb);
#pragma unroll
        for (int n = 0; n < 4; n++)
            bfv[n] = *(const short8*)(Bs + (size_t)(wc * 64 + n * 16 + fr) * 32 + kb);
#pragma unroll
        for (int m = 0; m < 4; m++)
#pragma unroll
            for (int n = 0; n < 4; n++)
                acc[m][n] = MFMA16(af[m], bfv[n], acc[m][n]);
        __syncthreads();
    }

    // epilogue: C/D frag layout col=lane&15, row=(lane>>4)*4+r  [m89]
    const int g4 = (lane >> 4) * 4;
    float bvv[4];
#pragma unroll
    for (int n = 0; n < 4; n++)
        bvv[n] = bias[n0 + wc * 64 + n * 16 + fr];

#pragma unroll
    for (int n = 0; n < 4; n++) {
        const int gn = n0 + wc * 64 + n * 16 + fr;
#pragma unroll
        for (int m = 0; m < 4; m++) {
            const int gm = m0 + wr * 64 + m * 16 + g4;
            if (MODE == MODE_RELU_BF16) {
                unsigned short* C = (unsigned short*)Cout;
#pragma unroll
                for (int r = 0; r < 4; r++)
                    C[(size_t)(gm + r) * N + gn] = f2bf(fmaxf(acc[m][n][r] + bvv[n], 0.f));
            } else { // MODE_F32 / MODE_LOGITS
                float* C = (float*)Cout;
#pragma unroll
                for (int r = 0; r < 4; r++)
                    C[(size_t)(gm + r) * N + gn] = acc[m][n][r] + bvv[n];
            }
        }
    }

    if (MODE == MODE_LOGITS) {
        // per-wave partial softmax stats over this wave's 64-col half.
        // masks 1..8 reduce over the 16-lane fr-group; correct because each
        // g-group owns DIFFERENT rows (row = ... + g4 + r).
        const int NPB = N >> 6;
        const int pb = (n0 >> 6) + wc;
#pragma unroll
        for (int m = 0; m < 4; m++)
#pragma unroll
            for (int r = 0; r < 4; r++) {
                float mx = -3.4e38f;
#pragma unroll
                for (int n = 0; n < 4; n++)
                    mx = fmaxf(mx, acc[m][n][r] + bvv[n]);
#pragma unroll
                for (int mm = 1; mm <= 8; mm <<= 1)
                    mx = fmaxf(mx, __shfl_xor(mx, mm, 64));
                float sm = 0.f;
#pragma unroll
                for (int n = 0; n < 4; n++)
                    sm += __expf(acc[m][n][r] + bvv[n] - mx);
#pragma unroll
                for (int mm = 1; mm <= 8; mm <<= 1)
                    sm += __shfl_xor(sm, mm, 64);
                if (fr == 0) {
                    const int row = m0 + wr * 64 + m * 16 + g4 + r;
                    pm[(size_t)row * NPB + pb] = mx;
                    pl[(size_t)row * NPB + pb] = sm;
                }
            }
    }
}

// ---------------------------------------------------------------------------
// Batched QKV GEMM: one dispatch, grid.z in {0:Q,1:K,2:V}.
// z<2: scatter to [B,H,T,HD] bf16.  z==2: scatter to V^T [B,H,HD,T] bf16.
// ---------------------------------------------------------------------------
struct QKVArgs {
    const unsigned short* wt[3];
    const float* b[3];
    unsigned short* o[3];
};

__global__ __launch_bounds__(256, 2) void k_gemm_qkv(
    const unsigned short* __restrict__ A, QKVArgs args, int M, int N, int K)
{
    __shared__ unsigned short As[128 * 32];
    __shared__ unsigned short Bs[128 * 32];
    const int z = blockIdx.z;
    const unsigned short* __restrict__ Bt = args.wt[z];
    const float* __restrict__ bias = args.b[z];
    unsigned short* __restrict__ C = args.o[z];

    const int tid = threadIdx.x;
    const int lane = tid & 63;
    const int w = tid >> 6;
    const int wr = w >> 1, wc = w & 1;

    const int gx = gridDim.x;
    const int swz = xcd_swz(blockIdx.y * gx + blockIdx.x, gx * gridDim.y);
    const int m0 = (swz / gx) * 128, n0 = (swz % gx) * 128;

    f32x4 acc[4][4];
#pragma unroll
    for (int i = 0; i < 4; i++)
#pragma unroll
        for (int j = 0; j < 4; j++)
            acc[i][j] = (f32x4){0.f, 0.f, 0.f, 0.f};

    const int crow = lane >> 2;
    const int ccol = (lane & 3) * 8;
    const unsigned short* gA0 = A  + (size_t)(m0 + w * 16 + crow) * K + ccol;
    const unsigned short* gA1 = A  + (size_t)(m0 + (w + 4) * 16 + crow) * K + ccol;
    const unsigned short* gB0 = Bt + (size_t)(n0 + w * 16 + crow) * K + ccol;
    const unsigned short* gB1 = Bt + (size_t)(n0 + (w + 4) * 16 + crow) * K + ccol;
    unsigned short* lA0 = As + w * 512;
    unsigned short* lA1 = As + (w + 4) * 512;
    unsigned short* lB0 = Bs + w * 512;
    unsigned short* lB1 = Bs + (w + 4) * 512;

    const int fr = lane & 15;
    const int kb = (lane >> 4) * 8;

    for (int k0 = 0; k0 < K; k0 += 32) {
        gl_lds16(gA0 + k0, lA0);
        gl_lds16(gA1 + k0, lA1);
        gl_lds16(gB0 + k0, lB0);
        gl_lds16(gB1 + k0, lB1);
        __syncthreads();
        short8 af[4], bfv[4];
#pragma unroll
        for (int m = 0; m < 4; m++)
            af[m] = *(const short8*)(As + (size_t)(wr * 64 + m * 16 + fr) * 32 + kb);
#pragma unroll
        for (int n = 0; n < 4; n++)
            bfv[n] = *(const short8*)(Bs + (size_t)(wc * 64 + n * 16 + fr) * 32 + kb);
#pragma unroll
        for (int m = 0; m < 4; m++)
#pragma unroll
            for (int n = 0; n < 4; n++)
                acc[m][n] = MFMA16(af[m], bfv[n], acc[m][n]);
        __syncthreads();
    }

    const int g4 = (lane >> 4) * 4;
#pragma unroll
    for (int n = 0; n < 4; n++) {
        const int gn = n0 + wc * 64 + n * 16 + fr;
        const float bv = bias[gn];
        const int hh = gn >> 6, hd = gn & 63;
#pragma unroll
        for (int m = 0; m < 4; m++) {
            const int gm = m0 + wr * 64 + m * 16 + g4;
            if (z < 2) {  // Q/K -> [B,H,T,HD]
#pragma unroll
                for (int r = 0; r < 4; r++) {
                    const int bb = (gm + r) >> 11, t = (gm + r) & (T_ - 1);
                    C[(((size_t)bb * H_ + hh) * T_ + t) * HD_ + hd] = f2bf(acc[m][n][r] + bv);
                }
            } else {      // V -> V^T [B,H,HD,T]
                const int bb = gm >> 11, t = gm & (T_ - 1);   // 4 consecutive t
                ushort4 pk;
                pk.x = f2bf(acc[m][n][0] + bv);
                pk.y = f2bf(acc[m][n][1] + bv);
                pk.z = f2bf(acc[m][n][2] + bv);
                pk.w = f2bf(acc[m][n][3] + bv);
                *(ushort4*)(&C[(((size_t)bb * H_ + hh) * HD_ + hd) * T_ + t]) = pk;
            }
        }
    }
}

// ---------------------------------------------------------------------------
// Flash attention, causal. 1 wave per 16 q rows, kv blocks of 64.
// Q,K: [BH,T,HD] bf16; Vt: [BH,HD,T] bf16; O: [B*T, D] bf16 (head cols)
// ---------------------------------------------------------------------------
__global__ __launch_bounds__(256, 2) void k_attention(
    const unsigned short* __restrict__ Q,
    const unsigned short* __restrict__ Km,
    const unsigned short* __restrict__ Vt,
    unsigned short* __restrict__ O)
{
    const int gx = gridDim.x;
    const int swz = xcd_swz(blockIdx.y * gx + blockIdx.x, gx * gridDim.y);
    const int bh = swz / gx, qb = swz % gx;
    const int w = threadIdx.x >> 6, lane = threadIdx.x & 63;
    const int g = lane >> 4, c = lane & 15;
    const int q0 = qb * 64 + w * 16;
    const unsigned short* Qh = Q  + (size_t)bh * T_ * HD_;
    const unsigned short* Kp = Km + (size_t)bh * T_ * HD_;
    const unsigned short* Vp = Vt + (size_t)bh * HD_ * T_;

    const short8 qf0 = *(const short8*)(Qh + (size_t)(q0 + c) * HD_ + g * 8);
    const short8 qf1 = *(const short8*)(Qh + (size_t)(q0 + c) * HD_ + 32 + g * 8);

    f32x4 o[4];
#pragma unroll
    for (int n = 0; n < 4; n++) o[n] = (f32x4){0.f, 0.f, 0.f, 0.f};
    float mrow[4] = {-3.4e38f, -3.4e38f, -3.4e38f, -3.4e38f};
    float lrow[4] = {0.f, 0.f, 0.f, 0.f};

    __shared__ unsigned short Plds[4][16 * 64];  // per-wave P tile
    unsigned short* pw = Plds[w];

    for (int kv0 = 0; kv0 <= q0 + 15; kv0 += 64) {
        // S = (Q K^T) / 8 with causal mask
        f32x4 s[4];
#pragma unroll
        for (int n = 0; n < 4; n++) {
            const short8 kf0 = *(const short8*)(Kp + (size_t)(kv0 + n * 16 + c) * HD_ + g * 8);
            const short8 kf1 = *(const short8*)(Kp + (size_t)(kv0 + n * 16 + c) * HD_ + 32 + g * 8);
            f32x4 z = (f32x4){0.f, 0.f, 0.f, 0.f};
            z = MFMA16(qf0, kf0, z);
            z = MFMA16(qf1, kf1, z);
            s[n] = z;
        }
        float mb[4];
#pragma unroll
        for (int r = 0; r < 4; r++) {
            const int qg = q0 + g * 4 + r;
            float best = -3.4e38f;
#pragma unroll
            for (int n = 0; n < 4; n++) {
                const int kv = kv0 + n * 16 + c;
                float val = s[n][r] * 0.125f;
                val = (kv > qg) ? -3.4e38f : val;
                s[n][r] = val;
                best = fmaxf(best, val);
            }
            mb[r] = best;
        }
#pragma unroll
        for (int mm = 1; mm <= 8; mm <<= 1)
#pragma unroll
            for (int r = 0; r < 4; r++)
                mb[r] = fmaxf(mb[r], __shfl_xor(mb[r], mm, 64));
        float alpha[4], ps[4];
#pragma unroll
        for (int r = 0; r < 4; r++) {
            const float mn = fmaxf(mrow[r], mb[r]);
            alpha[r] = __expf(mrow[r] - mn);
            mrow[r] = mn;
            ps[r] = 0.f;
        }
#pragma unroll
        for (int n = 0; n < 4; n++)
#pragma unroll
            for (int r = 0; r < 4; r++) {
                const float pv = __expf(s[n][r] - mrow[r]);
                s[n][r] = pv;
                ps[r] += pv;
            }
#pragma unroll
        for (int mm = 1; mm <= 8; mm <<= 1)
#pragma unroll
            for (int r = 0; r < 4; r++)
                ps[r] += __shfl_xor(ps[r], mm, 64);
#pragma unroll
        for (int r = 0; r < 4; r++)
            lrow[r] = lrow[r] * alpha[r] + ps[r];
#pragma unroll
        for (int n = 0; n < 4; n++)
#pragma unroll
            for (int r = 0; r < 4; r++)
                o[n][r] *= alpha[r];

        // P -> LDS (XOR-swizzled; same involution on write and read)
#pragma unroll
        for (int n = 0; n < 4; n++)
#pragma unroll
            for (int r = 0; r < 4; r++) {
                const int row = g * 4 + r;
                const int idx = (row * 64 + n * 16 + c) ^ ((row & 7) << 3);
                pw[idx] = f2bf(s[n][r]);
            }
        asm volatile("s_waitcnt lgkmcnt(0)" ::: "memory");
        __builtin_amdgcn_sched_barrier(0);
        const short8 pf0 = *(const short8*)(pw + ((c * 64 + g * 8) ^ ((c & 7) << 3)));
        const short8 pf1 = *(const short8*)(pw + ((c * 64 + 32 + g * 8) ^ ((c & 7) << 3)));
#pragma unroll
        for (int n = 0; n < 4; n++) {
            const short8 vf0 = *(const short8*)(Vp + (size_t)(n * 16 + c) * T_ + kv0 + g * 8);
            const short8 vf1 = *(const short8*)(Vp + (size_t)(n * 16 + c) * T_ + kv0 + 32 + g * 8);
            o[n] = MFMA16(pf0, vf0, o[n]);
            o[n] = MFMA16(pf1, vf1, o[n]);
        }
    }

    const int b = bh >> 4, h = bh & 15;
#pragma unroll
    for (int r = 0; r < 4; r++) {
        const float inv = 1.f / lrow[r];
        const size_t base = ((size_t)b * T_ + q0 + g * 4 + r) * D_ + h * 64;
#pragma unroll
        for (int n = 0; n < 4; n++)
            O[base + n * 16 + c] = f2bf(o[n][r] * inv);
    }
}

// ---------------------------------------------------------------------------
// LayerNorm (torch-faithful: unbiased std, (x-mean)/(std+eps)*g+b) -> bf16
// ---------------------------------------------------------------------------
__global__ __launch_bounds__(256) void k_layernorm(
    const float* __restrict__ X, const float* __restrict__ gamma,
    const float* __restrict__ beta, unsigned short* __restrict__ Y)
{
    const int row = blockIdx.x, tid = threadIdx.x;
    const float4 v = ((const float4*)(X + (size_t)row * D_))[tid];
    float s = v.x + v.y + v.z + v.w;
#pragma unroll
    for (int m = 1; m < 64; m <<= 1) s += __shfl_xor(s, m, 64);
    __shared__ float red[4], red2[4];
    if (!(tid & 63)) red[tid >> 6] = s;
    __syncthreads();
    const float mean = (red[0] + red[1] + red[2] + red[3]) * (1.f / 1024.f);
    const float a0 = v.x - mean, a1 = v.y - mean, a2 = v.z - mean, a3 = v.w - mean;
    float ss = a0 * a0 + a1 * a1 + a2 * a2 + a3 * a3;
#pragma unroll
    for (int m = 1; m < 64; m <<= 1) ss += __shfl_xor(ss, m, 64);
    if (!(tid & 63)) red2[tid >> 6] = ss;
    __syncthreads();
    const float var = (red2[0] + red2[1] + red2[2] + red2[3]) * (1.f / 1023.f);
    const float inv = 1.f / (sqrtf(var) + 1e-6f);
    const float4 gg = ((const float4*)gamma)[tid];
    const float4 bb = ((const float4*)beta)[tid];
    ushort4 ov;
    ov.x = f2bf(a0 * inv * gg.x + bb.x);
    ov.y = f2bf(a1 * inv * gg.y + bb.y);
    ov.z = f2bf(a2 * inv * gg.z + bb.z);
    ov.w = f2bf(a3 * inv * gg.w + bb.w);
    *(ushort4*)(Y + (size_t)row * D_ + tid * 4) = ov;
}

// ---------------------------------------------------------------------------
// Softmax partial-stat reduce (per row over NPB=V/64 partials) + normalize
// ---------------------------------------------------------------------------
__global__ __launch_bounds__(256) void k_softmax_reduce(
    const float* __restrict__ pm, const float* __restrict__ pl,
    float* __restrict__ rowm, float* __restrict__ rowl)
{
    const int row = blockIdx.x, tid = threadIdx.x;
    const int NPB = V_ >> 6;   // 500
    const float* pmr = pm + (size_t)row * NPB;
    const float* plr = pl + (size_t)row * NPB;
    float mx = -3.4e38f;
    for (int i = tid; i < NPB; i += 256) mx = fmaxf(mx, pmr[i]);
#pragma unroll
    for (int m = 1; m < 64; m <<= 1) mx = fmaxf(mx, __shfl_xor(mx, m, 64));
    __shared__ float red[4], red2[4];
    if (!(tid & 63)) red[tid >> 6] = mx;
    __syncthreads();
    mx = fmaxf(fmaxf(red[0], red[1]), fmaxf(red[2], red[3]));
    float s = 0.f;
    for (int i = tid; i < NPB; i += 256) s += plr[i] * __expf(pmr[i] - mx);
#pragma unroll
    for (int m = 1; m < 64; m <<= 1) s += __shfl_xor(s, m, 64);
    if (!(tid & 63)) red2[tid >> 6] = s;
    __syncthreads();
    if (tid == 0) {
        rowm[row] = mx;
        rowl[row] = red2[0] + red2[1] + red2[2] + red2[3];
    }
}

__global__ __launch_bounds__(256) void k_softmax_norm(
    float* __restrict__ L, const float* __restrict__ rowm, const float* __restrict__ rowl)
{
    const unsigned total = (unsigned)BT_ * (V_ / 4);
    float4* p = (float4*)L;
    for (unsigned i = blockIdx.x * 256u + threadIdx.x; i < total; i += gridDim.x * 256u) {
        const unsigned row = i / (V_ / 4);
        float4 v = p[i];
        const float mx = rowm[row], inv = 1.f / rowl[row];
        v.x = __expf(v.x - mx) * inv;
        v.y = __expf(v.y - mx) * inv;
        v.z = __expf(v.z - mx) * inv;
        v.w = __expf(v.w - mx) * inv;
        p[i] = v;
    }
}

// ---------------------------------------------------------------------------
extern "C" void kernel_launch(void* const* d_in, const int* in_sizes, int n_in,
                              void* d_out, int out_size, void* d_ws, size_t ws_size,
                              hipStream_t stream)
{
    const int*   x   = (const int*)  d_in[0];
    const float* emb = (const float*)d_in[1];
    const float* Wq  = (const float*)d_in[2];
    const float* bq  = (const float*)d_in[3];
    const float* Wk  = (const float*)d_in[4];
    const float* bk  = (const float*)d_in[5];
    const float* Wv  = (const float*)d_in[6];
    const float* bv  = (const float*)d_in[7];
    const float* Wo  = (const float*)d_in[8];
    const float* bo  = (const float*)d_in[9];
    const float* g1  = (const float*)d_in[10];
    const float* be1 = (const float*)d_in[11];
    const float* W1  = (const float*)d_in[12];
    const float* bf1 = (const float*)d_in[13];
    const float* W2  = (const float*)d_in[14];
    const float* bf2 = (const float*)d_in[15];
    const float* g2  = (const float*)d_in[16];
    const float* be2 = (const float*)d_in[17];
    const float* Wl  = (const float*)d_in[18];
    const float* bl  = (const float*)d_in[19];
    float* out = (float*)d_out;

    // workspace carve (aliased regions; ~170 MB total)
    char* p = (char*)d_ws;
    auto alloc = [&](size_t bytes) {
        char* r = p;
        p += (bytes + 255) & ~(size_t)255;
        return r;
    };
    const size_t NE = (size_t)BT_ * D_;   // 4,194,304 elements
    // region0: h | q | k | vt  (later reused as ffn1 [BT,F] bf16 = same bytes)
    unsigned short* region0 = (unsigned short*)alloc(4 * NE * 2);
    unsigned short* h_bf    = region0;
    unsigned short* q_bf    = region0 + NE;
    unsigned short* k_bf    = region0 + 2 * NE;
    unsigned short* vt_bf   = region0 + 3 * NE;
    unsigned short* ffn1_bf = region0;
    // region1: o_bf, later ln1_bf, later ln2_bf
    unsigned short* region1 = (unsigned short*)alloc(NE * 2);
    unsigned short* o_bf   = region1;
    unsigned short* ln1_bf = region1;
    unsigned short* ln2_bf = region1;
    // region2: attn_f, later ffn2_f
    float* region2 = (float*)alloc(NE * 4);
    float* attn_f = region2;
    float* ffn2_f = region2;
    // weights (bf16, transposed)
    unsigned short* wq_t = (unsigned short*)alloc((size_t)D_ * D_ * 2);
    unsigned short* wk_t = (unsigned short*)alloc((size_t)D_ * D_ * 2);
    unsigned short* wv_t = (unsigned short*)alloc((size_t)D_ * D_ * 2);
    unsigned short* wo_t = (unsigned short*)alloc((size_t)D_ * D_ * 2);
    unsigned short* w1_t = (unsigned short*)alloc((size_t)D_ * F_ * 2);
    unsigned short* w2_t = (unsigned short*)alloc((size_t)F_ * D_ * 2);
    unsigned short* wl_t = (unsigned short*)alloc((size_t)D_ * V_ * 2);
    float* pm   = (float*)alloc((size_t)BT_ * (V_ >> 6) * 4);   // 8 MB
    float* pl   = (float*)alloc((size_t)BT_ * (V_ >> 6) * 4);   // 8 MB
    float* rowm = (float*)alloc(BT_ * 4);
    float* rowl = (float*)alloc(BT_ * 4);

    const dim3 blk(256);

    // 1. weight conversions/transposes (4 D×D batched + W1 + W2 + Wl)
    TP4 tp;
    tp.src[0] = Wq; tp.dst[0] = wq_t;
    tp.src[1] = Wk; tp.dst[1] = wk_t;
    tp.src[2] = Wv; tp.dst[2] = wv_t;
    tp.src[3] = Wo; tp.dst[3] = wo_t;
    k_transpose_cvt4<<<dim3(D_ / 64, D_ / 64, 4), blk, 0, stream>>>(tp, D_, D_);
    k_transpose_cvt<<<dim3(F_ / 64, D_ / 64), blk, 0, stream>>>(W1, w1_t, D_, F_);
    k_transpose_cvt<<<dim3(D_ / 64, F_ / 64), blk, 0, stream>>>(W2, w2_t, F_, D_);
    k_transpose_cvt<<<dim3(V_ / 64, D_ / 64), blk, 0, stream>>>(Wl, wl_t, D_, V_);

    // 2. embedding + positional encoding
    k_embed<<<BT_, blk, 0, stream>>>(x, emb, h_bf);

    // 3. QKV projections, one batched dispatch
    QKVArgs qa;
    qa.wt[0] = wq_t; qa.b[0] = bq; qa.o[0] = q_bf;
    qa.wt[1] = wk_t; qa.b[1] = bk; qa.o[1] = k_bf;
    qa.wt[2] = wv_t; qa.b[2] = bv; qa.o[2] = vt_bf;
    k_gemm_qkv<<<dim3(D_ / 128, BT_ / 128, 3), blk, 0, stream>>>(h_bf, qa, BT_, D_, D_);

    // 4. causal flash attention
    k_attention<<<dim3(T_ / 64, B_ * H_), blk, 0, stream>>>(q_bf, k_bf, vt_bf, o_bf);

    // 5. output projection
    k_gemm<MODE_F32><<<dim3(D_ / 128, BT_ / 128), blk, 0, stream>>>(
        o_bf, wo_t, bo, attn_f, BT_, D_, D_, nullptr, nullptr);

    // 6. LN1
    k_layernorm<<<BT_, blk, 0, stream>>>(attn_f, g1, be1, ln1_bf);

    // 7. FFN1 + ReLU
    k_gemm<MODE_RELU_BF16><<<dim3(F_ / 128, BT_ / 128), blk, 0, stream>>>(
        ln1_bf, w1_t, bf1, ffn1_bf, BT_, F_, D_, nullptr, nullptr);

    // 8. FFN2
    k_gemm<MODE_F32><<<dim3(D_ / 128, BT_ / 128), blk, 0, stream>>>(
        ffn1_bf, w2_t, bf2, ffn2_f, BT_, D_, F_, nullptr, nullptr);

    // 9. LN2
    k_layernorm<<<BT_, blk, 0, stream>>>(ffn2_f, g2, be2, ln2_bf);

    // 10. logits -> d_out, with fused per-wave softmax partials
    k_gemm<MODE_LOGITS><<<dim3(V_ / 128, BT_ / 128), blk, 0, stream>>>(
        ln2_bf, wl_t, bl, out, BT_, V_, D_, pm, pl);

    // 11. merge partials -> row max / row sum
    k_softmax_reduce<<<BT_, blk, 0, stream>>>(pm, pl, rowm, rowl);

    // 12. normalize in-place on d_out
    k_softmax_norm<<<8192, blk, 0, stream>>>(out, rowm, rowl);
}